// Round 11
// baseline (206.119 us; speedup 1.0000x reference)
//
#include <hip/hip_runtime.h>

#define HW    16384   // 128*128
#define Wh    128
#define Cin   64
#define C2    32
#define HW4   4096    // 64*64

typedef short short8 __attribute__((ext_vector_type(8)));     // 8 bf16 = 4 VGPRs
typedef float float4v __attribute__((ext_vector_type(4)));
typedef unsigned uint4v __attribute__((ext_vector_type(4)));

#define LOG2E 1.44269504f
#define OFFE  43.2808512f   // 30*log2(e): exp(s-30) == exp2(s*log2e - OFFE)

__device__ __forceinline__ unsigned pack2bf16(float lo, float hi) {
  unsigned ul = __builtin_bit_cast(unsigned, lo);
  unsigned uh = __builtin_bit_cast(unsigned, hi);
  ul = (ul + 0x7fffu + ((ul >> 16) & 1u)) >> 16;
  uh = (uh + 0x7fffu + ((uh >> 16) & 1u)) & 0xffff0000u;
  return ul | uh;
}
__device__ __forceinline__ unsigned short f2bf(float f) {
  unsigned u = __builtin_bit_cast(unsigned, f);
  return (unsigned short)((u + 0x7fffu + ((u >> 16) & 1u)) >> 16);
}
// RTZ-truncate two fp32 to bf16, lo in [15:0], hi in [31:16]
__device__ __forceinline__ unsigned packtrunc(float lo, float hi) {
  return __builtin_amdgcn_perm(__builtin_bit_cast(unsigned, hi),
                               __builtin_bit_cast(unsigned, lo), 0x07060302u);
}

// ---------------------------------------------------------------------------
// Kernel 0: weight repack. wAll[og][c][24] = {theta(8, x log2e), phi(8), g(8)}
// ---------------------------------------------------------------------------
__global__ __launch_bounds__(256) void repack_w_kern(
    const float* __restrict__ wt, const float* __restrict__ bt,
    const float* __restrict__ wp, const float* __restrict__ bp,
    const float* __restrict__ wg, const float* __restrict__ bg,
    float* __restrict__ wAll, float* __restrict__ bAll) {
  int idx = blockIdx.x * 256 + threadIdx.x;
  if (idx < 6144) {
    int og = idx / 1536, rem = idx % 1536;
    int c = rem / 24, j = rem % 24;
    int o = og * 8 + (j & 7);
    float v;
    if (j < 8)       v = wt[o * Cin + c] * LOG2E;
    else if (j < 16) v = wp[o * Cin + c];
    else             v = wg[o * Cin + c];
    wAll[idx] = v;
  } else if (idx < 6240) {
    int i2 = idx - 6144;
    int og = i2 / 24, j = i2 % 24;
    int o = og * 8 + (j & 7);
    bAll[i2] = (j < 8) ? bt[o] * LOG2E : (j < 16 ? bp[o] : bg[o]);
  }
}

// ---------------------------------------------------------------------------
// Kernel 1: FUSED theta+phi+g conv (+2x2 maxpool), 1 px/thread, 1024 blocks.
// 8-deep load batch. K stored with S^T row perm; Vt transposed via LDS.
// ---------------------------------------------------------------------------
__global__ __launch_bounds__(256) void conv_qkv_kern(
    const float* __restrict__ x, const float* __restrict__ wAll,
    const float* __restrict__ bAll, unsigned short* __restrict__ Q,
    unsigned short* __restrict__ K, unsigned short* __restrict__ Vt) {
  __shared__ unsigned short smV[8][64];          // 1 KB
  int tid = threadIdx.x;
  int og = blockIdx.y, bz = blockIdx.z;
  int pp = blockIdx.x * 64 + (tid >> 2);         // pooled pixel
  int i = pp >> 6, j = pp & 63;
  int row = 2 * i + ((tid >> 1) & 1);
  int col = 2 * j + (tid & 1);
  int p = row * Wh + col;                        // full-res pixel
  const float* xb = x + (size_t)bz * Cin * HW + p;
  const float* wc = wAll + og * 1536;            // uniform -> s_load
  const float* bb = bAll + og * 24;
  float acc[24];
#pragma unroll
  for (int k = 0; k < 24; ++k) acc[k] = bb[k];
  for (int cb = 0; cb < Cin; cb += 8) {
    float xv[8];
#pragma unroll
    for (int u = 0; u < 8; ++u)                  // 8 loads in flight
      xv[u] = xb[(size_t)(cb + u) * HW];
#pragma unroll
    for (int u = 0; u < 8; ++u) {
#pragma unroll
      for (int k = 0; k < 24; ++k)
        acc[k] = fmaf(wc[(cb + u) * 24 + k], xv[u], acc[k]);
    }
  }
  // theta -> Q
  {
    uint4 up;
    up.x = pack2bf16(acc[0], acc[1]); up.y = pack2bf16(acc[2], acc[3]);
    up.z = pack2bf16(acc[4], acc[5]); up.w = pack2bf16(acc[6], acc[7]);
    *(uint4*)(Q + ((size_t)bz * HW + p) * C2 + og * 8) = up;
  }
  // 2x2 maxpool across lane-mates {4j..4j+3}
  float aP[8], aG[8];
#pragma unroll
  for (int o = 0; o < 8; ++o) {
    float vp = acc[8 + o], vg = acc[16 + o];
    vp = fmaxf(vp, __shfl_xor(vp, 1)); vp = fmaxf(vp, __shfl_xor(vp, 2));
    vg = fmaxf(vg, __shfl_xor(vg, 1)); vg = fmaxf(vg, __shfl_xor(vg, 2));
    aP[o] = vp; aG[o] = vg;
  }
  if ((tid & 3) == 0) {
    int loc = pp & 31, tile = pp >> 5;
    int prow = ((loc & 4) << 2) + ((loc >> 3) << 2) + (loc & 3);   // S^T perm
    uint4 up;
    up.x = pack2bf16(aP[0], aP[1]); up.y = pack2bf16(aP[2], aP[3]);
    up.z = pack2bf16(aP[4], aP[5]); up.w = pack2bf16(aP[6], aP[7]);
    *(uint4*)(K + ((size_t)bz * HW4 + tile * 32 + prow) * C2 + og * 8) = up;
#pragma unroll
    for (int o = 0; o < 8; ++o) smV[o][tid >> 2] = f2bf(aG[o]);
  }
  __syncthreads();
  // coalesced V store: thread t -> channel t>>5, dword t&31 (2 keys)
  {
    int ch = tid >> 5, idx = tid & 31;
    unsigned v = ((unsigned*)smV)[ch * 32 + idx];
    *(unsigned*)(Vt + (size_t)bz * C2 * HW4 + (size_t)(og * 8 + ch) * HW4 +
                 blockIdx.x * 64 + 2 * idx) = v;
  }
}

// ---------------------------------------------------------------------------
// Kernel 2: MFMA flash attention, STAGE-PIPELINED + FUSED OUTPUT CONV.
// Per iteration: loads(t) -> process(t-1) [exp/pack/PV on the PREVIOUS
// tile's scores — independent of this tile's loads AND a full tile away
// from its producing MFMA] -> QK MFMAs(t). Breaks the per-tile
// MFMA->exp->MFMA phase-lock that kept both pipes <28% (R7-R10).
// Epilogue: all 4 waves dump partials to LDS (stride 34: 8B-aligned float2,
// 2-way banks = free), one barrier, then 32->64 out-conv + bias + residual
// written straight to `out` (conv_out kernel + Y round-trip eliminated).
// ---------------------------------------------------------------------------
struct KVT { short8 ka, kh, va, vh; };

__device__ __forceinline__ KVT ldkv(const unsigned short* kt,
                                    const unsigned short* vt,
                                    int l16, int quad) {
  KVT r;
  r.ka = *(const short8*)(kt + (size_t)l16 * C2 + quad * 8);
  r.kh = *(const short8*)(kt + (size_t)(16 + l16) * C2 + quad * 8);
  r.va = *(const short8*)(vt + (size_t)l16 * HW4 + quad * 8);
  r.vh = *(const short8*)(vt + (size_t)(16 + l16) * HW4 + quad * 8);
  return r;
}

__global__ __launch_bounds__(256, 4) void attn_mfma_kern(
    const unsigned short* __restrict__ Qb, const unsigned short* __restrict__ Kb,
    const unsigned short* __restrict__ Vt, const float* __restrict__ x,
    const float* __restrict__ wout, const float* __restrict__ bout,
    float* __restrict__ out) {
  __shared__ float smY[4][32][34];   // stride 34: float2-aligned, 2-way banks
  __shared__ float smL[4][32];
  int lane = threadIdx.x & 63;
  int wv = threadIdx.x >> 6;
  int quad = lane >> 4, l16 = lane & 15;
  int bz = blockIdx.y;
  int qrow0 = blockIdx.x * 32;

  short8 qf0 = *(const short8*)(Qb + ((size_t)bz * HW + qrow0 + l16) * C2 + quad * 8);
  short8 qf1 = *(const short8*)(Qb + ((size_t)bz * HW + qrow0 + 16 + l16) * C2 + quad * 8);
  const unsigned short* kb = Kb + ((size_t)bz * HW4 + wv * 1024) * C2;
  const unsigned short* vb = Vt + (size_t)bz * C2 * HW4 + wv * 1024;

  short8 ones;
#pragma unroll
  for (int i = 0; i < 8; ++i) ones[i] = (short)0x3F80;  // bf16 1.0

  float4v z = {0.f, 0.f, 0.f, 0.f};
  float4v y00 = z, y10 = z, y20 = z, y01 = z, y11 = z, y21 = z;
  float4v moff = {-OFFE, -OFFE, -OFFE, -OFFE};

  // exp/pack/PV for one tile's staged scores (6 MFMAs, 16 exp2, 8 packs)
  auto process = [&](float4v s00, float4v s10, float4v s01, float4v s11,
                     short8 va, short8 vh) {
    {
      float e0 = __builtin_amdgcn_exp2f(s00[0]), e1 = __builtin_amdgcn_exp2f(s00[1]);
      float e2 = __builtin_amdgcn_exp2f(s00[2]), e3 = __builtin_amdgcn_exp2f(s00[3]);
      float f0 = __builtin_amdgcn_exp2f(s10[0]), f1 = __builtin_amdgcn_exp2f(s10[1]);
      float f2 = __builtin_amdgcn_exp2f(s10[2]), f3 = __builtin_amdgcn_exp2f(s10[3]);
      uint4v d = {packtrunc(e0, e1), packtrunc(e2, e3),
                  packtrunc(f0, f1), packtrunc(f2, f3)};
      short8 pf0 = __builtin_bit_cast(short8, d);
      y00 = __builtin_amdgcn_mfma_f32_16x16x32_bf16(pf0, va,   y00, 0, 0, 0);
      y10 = __builtin_amdgcn_mfma_f32_16x16x32_bf16(pf0, vh,   y10, 0, 0, 0);
      y20 = __builtin_amdgcn_mfma_f32_16x16x32_bf16(pf0, ones, y20, 0, 0, 0);
    }
    {
      float e0 = __builtin_amdgcn_exp2f(s01[0]), e1 = __builtin_amdgcn_exp2f(s01[1]);
      float e2 = __builtin_amdgcn_exp2f(s01[2]), e3 = __builtin_amdgcn_exp2f(s01[3]);
      float f0 = __builtin_amdgcn_exp2f(s11[0]), f1 = __builtin_amdgcn_exp2f(s11[1]);
      float f2 = __builtin_amdgcn_exp2f(s11[2]), f3 = __builtin_amdgcn_exp2f(s11[3]);
      uint4v d = {packtrunc(e0, e1), packtrunc(e2, e3),
                  packtrunc(f0, f1), packtrunc(f2, f3)};
      short8 pf1 = __builtin_bit_cast(short8, d);
      y01 = __builtin_amdgcn_mfma_f32_16x16x32_bf16(pf1, va,   y01, 0, 0, 0);
      y11 = __builtin_amdgcn_mfma_f32_16x16x32_bf16(pf1, vh,   y11, 0, 0, 0);
      y21 = __builtin_amdgcn_mfma_f32_16x16x32_bf16(pf1, ones, y21, 0, 0, 0);
    }
  };

  // prologue: scores for tile 0
  KVT cur = ldkv(kb, vb, l16, quad);
  float4v sp00 = __builtin_amdgcn_mfma_f32_16x16x32_bf16(cur.ka, qf0, moff, 0, 0, 0);
  float4v sp10 = __builtin_amdgcn_mfma_f32_16x16x32_bf16(cur.kh, qf0, moff, 0, 0, 0);
  float4v sp01 = __builtin_amdgcn_mfma_f32_16x16x32_bf16(cur.ka, qf1, moff, 0, 0, 0);
  float4v sp11 = __builtin_amdgcn_mfma_f32_16x16x32_bf16(cur.kh, qf1, moff, 0, 0, 0);
  short8 pva = cur.va, pvh = cur.vh;

  for (int t = 1; t < 32; ++t) {
    KVT nx = ldkv(kb + (size_t)t * 32 * C2, vb + t * 32, l16, quad);
    process(sp00, sp10, sp01, sp11, pva, pvh);    // tile t-1, no dep on nx
    sp00 = __builtin_amdgcn_mfma_f32_16x16x32_bf16(nx.ka, qf0, moff, 0, 0, 0);
    sp10 = __builtin_amdgcn_mfma_f32_16x16x32_bf16(nx.kh, qf0, moff, 0, 0, 0);
    sp01 = __builtin_amdgcn_mfma_f32_16x16x32_bf16(nx.ka, qf1, moff, 0, 0, 0);
    sp11 = __builtin_amdgcn_mfma_f32_16x16x32_bf16(nx.kh, qf1, moff, 0, 0, 0);
    pva = nx.va; pvh = nx.vh;
  }
  process(sp00, sp10, sp01, sp11, pva, pvh);      // tile 31

  // ---- dump partials (all 4 waves) ----
#pragma unroll
  for (int r = 0; r < 4; ++r) {
    int lr0 = quad * 4 + r, lr1 = lr0 + 16;
    smY[wv][lr0][l16] = y00[r];  smY[wv][lr0][16 + l16] = y10[r];
    smY[wv][lr1][l16] = y01[r];  smY[wv][lr1][16 + l16] = y11[r];
  }
  if (l16 == 0) {
#pragma unroll
    for (int r = 0; r < 4; ++r) {
      smL[wv][quad * 4 + r] = y20[r];        // ones-MFMA: cols identical
      smL[wv][16 + quad * 4 + r] = y21[r];
    }
  }
  __syncthreads();

  // ---- fused output conv: thread = (pixel pxl, 8-channel group cog) ----
  {
    int tid = threadIdx.x;
    int pxl = tid & 31;            // q-row within block = pixel
    int cog = tid >> 5;            // 0..7 -> out channels cog*8..+7
    float yv[32];
#pragma unroll
    for (int o2 = 0; o2 < 16; ++o2) {
      float2 a = *(float2*)&smY[0][pxl][o2 * 2];
      float2 b2 = *(float2*)&smY[1][pxl][o2 * 2];
      float2 c = *(float2*)&smY[2][pxl][o2 * 2];
      float2 d2 = *(float2*)&smY[3][pxl][o2 * 2];
      yv[2 * o2]     = (a.x + b2.x) + (c.x + d2.x);
      yv[2 * o2 + 1] = (a.y + b2.y) + (c.y + d2.y);
    }
    float linv = 1.f / (smL[0][pxl] + smL[1][pxl] + smL[2][pxl] + smL[3][pxl]);
#pragma unroll
    for (int o = 0; o < 32; ++o) yv[o] *= linv;
    size_t pofs = (size_t)bz * Cin * HW + qrow0 + pxl;
    const float* xb = x + pofs;
    float* ob = out + pofs;
#pragma unroll
    for (int i = 0; i < 8; ++i) {
      int co = cog * 8 + i;
      const float4* wco = (const float4*)(wout + co * C2);
      float s = bout[co];
#pragma unroll
      for (int o4 = 0; o4 < 8; ++o4) {
        float4 w4 = wco[o4];
        s = fmaf(w4.x, yv[4 * o4], s);
        s = fmaf(w4.y, yv[4 * o4 + 1], s);
        s = fmaf(w4.z, yv[4 * o4 + 2], s);
        s = fmaf(w4.w, yv[4 * o4 + 3], s);
      }
      ob[(size_t)co * HW] = s + xb[(size_t)co * HW];  // 128B segs per co
    }
  }
}

// ---------------------------------------------------------------------------
extern "C" void kernel_launch(void* const* d_in, const int* in_sizes, int n_in,
                              void* d_out, int out_size, void* d_ws, size_t ws_size,
                              hipStream_t stream) {
  const float* x       = (const float*)d_in[0];
  const float* w_theta = (const float*)d_in[1];
  const float* b_theta = (const float*)d_in[2];
  const float* w_phi   = (const float*)d_in[3];
  const float* b_phi   = (const float*)d_in[4];
  const float* w_g     = (const float*)d_in[5];
  const float* b_g     = (const float*)d_in[6];
  const float* w_out   = (const float*)d_in[7];
  const float* b_out   = (const float*)d_in[8];
  float* out = (float*)d_out;

  unsigned short* Qb = (unsigned short*)d_ws;                  // 4 MB bf16
  unsigned short* Kb = Qb + (size_t)4 * HW * C2;               // 1 MB
  unsigned short* Vt = Kb + (size_t)4 * HW4 * C2;              // 1 MB
  float* wAll = (float*)(Vt + (size_t)4 * HW4 * C2);           // 6144 f
  float* bAll = wAll + 6144;                                   // 96 f

  repack_w_kern<<<25, 256, 0, stream>>>(w_theta, b_theta, w_phi, b_phi,
                                        w_g, b_g, wAll, bAll);
  conv_qkv_kern<<<dim3(64, 4, 4), 256, 0, stream>>>(x, wAll, bAll, Qb, Kb, Vt);
  attn_mfma_kern<<<dim3(HW / 32, 4), 256, 0, stream>>>(
      Qb, Kb, Vt, x, w_out, b_out, out);
}

// Round 12
// 163.048 us; speedup vs baseline: 1.2642x; 1.2642x over previous
//
#include <hip/hip_runtime.h>

#define HW    16384   // 128*128
#define Wh    128
#define Cin   64
#define C2    32
#define HW4   4096    // 64*64

typedef short short8 __attribute__((ext_vector_type(8)));     // 8 bf16 = 4 VGPRs
typedef float float4v __attribute__((ext_vector_type(4)));
typedef unsigned uint4v __attribute__((ext_vector_type(4)));

#define LOG2E 1.44269504f
#define OFFE  43.2808512f   // 30*log2(e): exp(s-30) == exp2(s*log2e - OFFE)

__device__ __forceinline__ unsigned pack2bf16(float lo, float hi) {
  unsigned ul = __builtin_bit_cast(unsigned, lo);
  unsigned uh = __builtin_bit_cast(unsigned, hi);
  ul = (ul + 0x7fffu + ((ul >> 16) & 1u)) >> 16;
  uh = (uh + 0x7fffu + ((uh >> 16) & 1u)) & 0xffff0000u;
  return ul | uh;
}
__device__ __forceinline__ unsigned short f2bf(float f) {
  unsigned u = __builtin_bit_cast(unsigned, f);
  return (unsigned short)((u + 0x7fffu + ((u >> 16) & 1u)) >> 16);
}
// RTZ-truncate two fp32 to bf16, lo in [15:0], hi in [31:16]
__device__ __forceinline__ unsigned packtrunc(float lo, float hi) {
  return __builtin_amdgcn_perm(__builtin_bit_cast(unsigned, hi),
                               __builtin_bit_cast(unsigned, lo), 0x07060302u);
}

// ---------------------------------------------------------------------------
// Kernel 0: weight repack. wAll[og][c][24] = {theta(8, x log2e), phi(8), g(8)}
// ---------------------------------------------------------------------------
__global__ __launch_bounds__(256) void repack_w_kern(
    const float* __restrict__ wt, const float* __restrict__ bt,
    const float* __restrict__ wp, const float* __restrict__ bp,
    const float* __restrict__ wg, const float* __restrict__ bg,
    float* __restrict__ wAll, float* __restrict__ bAll) {
  int idx = blockIdx.x * 256 + threadIdx.x;
  if (idx < 6144) {
    int og = idx / 1536, rem = idx % 1536;
    int c = rem / 24, j = rem % 24;
    int o = og * 8 + (j & 7);
    float v;
    if (j < 8)       v = wt[o * Cin + c] * LOG2E;
    else if (j < 16) v = wp[o * Cin + c];
    else             v = wg[o * Cin + c];
    wAll[idx] = v;
  } else if (idx < 6240) {
    int i2 = idx - 6144;
    int og = i2 / 24, j = i2 % 24;
    int o = og * 8 + (j & 7);
    bAll[i2] = (j < 8) ? bt[o] * LOG2E : (j < 16 ? bp[o] : bg[o]);
  }
}

// ---------------------------------------------------------------------------
// Kernel 1: FUSED theta+phi+g conv (+2x2 maxpool), 1 px/thread, 1024 blocks.
// 8-deep load batch. K stored with S^T row perm; Vt transposed via LDS.
// ---------------------------------------------------------------------------
__global__ __launch_bounds__(256) void conv_qkv_kern(
    const float* __restrict__ x, const float* __restrict__ wAll,
    const float* __restrict__ bAll, unsigned short* __restrict__ Q,
    unsigned short* __restrict__ K, unsigned short* __restrict__ Vt) {
  __shared__ unsigned short smV[8][64];          // 1 KB
  int tid = threadIdx.x;
  int og = blockIdx.y, bz = blockIdx.z;
  int pp = blockIdx.x * 64 + (tid >> 2);         // pooled pixel
  int i = pp >> 6, j = pp & 63;
  int row = 2 * i + ((tid >> 1) & 1);
  int col = 2 * j + (tid & 1);
  int p = row * Wh + col;                        // full-res pixel
  const float* xb = x + (size_t)bz * Cin * HW + p;
  const float* wc = wAll + og * 1536;            // uniform -> s_load
  const float* bb = bAll + og * 24;
  float acc[24];
#pragma unroll
  for (int k = 0; k < 24; ++k) acc[k] = bb[k];
  for (int cb = 0; cb < Cin; cb += 8) {
    float xv[8];
#pragma unroll
    for (int u = 0; u < 8; ++u)                  // 8 loads in flight
      xv[u] = xb[(size_t)(cb + u) * HW];
#pragma unroll
    for (int u = 0; u < 8; ++u) {
#pragma unroll
      for (int k = 0; k < 24; ++k)
        acc[k] = fmaf(wc[(cb + u) * 24 + k], xv[u], acc[k]);
    }
  }
  // theta -> Q
  {
    uint4 up;
    up.x = pack2bf16(acc[0], acc[1]); up.y = pack2bf16(acc[2], acc[3]);
    up.z = pack2bf16(acc[4], acc[5]); up.w = pack2bf16(acc[6], acc[7]);
    *(uint4*)(Q + ((size_t)bz * HW + p) * C2 + og * 8) = up;
  }
  // 2x2 maxpool across lane-mates {4j..4j+3}
  float aP[8], aG[8];
#pragma unroll
  for (int o = 0; o < 8; ++o) {
    float vp = acc[8 + o], vg = acc[16 + o];
    vp = fmaxf(vp, __shfl_xor(vp, 1)); vp = fmaxf(vp, __shfl_xor(vp, 2));
    vg = fmaxf(vg, __shfl_xor(vg, 1)); vg = fmaxf(vg, __shfl_xor(vg, 2));
    aP[o] = vp; aG[o] = vg;
  }
  if ((tid & 3) == 0) {
    int loc = pp & 31, tile = pp >> 5;
    int prow = ((loc & 4) << 2) + ((loc >> 3) << 2) + (loc & 3);   // S^T perm
    uint4 up;
    up.x = pack2bf16(aP[0], aP[1]); up.y = pack2bf16(aP[2], aP[3]);
    up.z = pack2bf16(aP[4], aP[5]); up.w = pack2bf16(aP[6], aP[7]);
    *(uint4*)(K + ((size_t)bz * HW4 + tile * 32 + prow) * C2 + og * 8) = up;
#pragma unroll
    for (int o = 0; o < 8; ++o) smV[o][tid >> 2] = f2bf(aG[o]);
  }
  __syncthreads();
  // coalesced V store: thread t -> channel t>>5, dword t&31 (2 keys)
  {
    int ch = tid >> 5, idx = tid & 31;
    unsigned v = ((unsigned*)smV)[ch * 32 + idx];
    *(unsigned*)(Vt + (size_t)bz * C2 * HW4 + (size_t)(og * 8 + ch) * HW4 +
                 blockIdx.x * 64 + 2 * idx) = v;
  }
}

// ---------------------------------------------------------------------------
// Kernel 2: MFMA flash attention — 64 Q-ROWS (4 fragments) PER WAVE.
// Instead of pipelining (neutral 3x: R9/R10/R11), raise per-wave ILP: per
// 32-key tile the same 4 K/V loads now feed 4 INDEPENDENT QK->exp->PV chains
// (20 MFMA, 32 exp2) — frag f+1's QK issues while frag f's exp runs, and
// chain latency is amortized over 2x the FLOPs. Wave count halves.
// S^T trick throughout: P emerges in PV A-layout in registers; ones-MFMA
// computes row-sums l on the MFMA pipe, row-aligned with y.
// (256,4)=128-VGPR budget; ~105 used; spill signature = WRITE_SIZE > 8.2MB.
// ---------------------------------------------------------------------------
__global__ __launch_bounds__(256, 4) void attn_mfma_kern(
    const unsigned short* __restrict__ Qb, const unsigned short* __restrict__ Kb,
    const unsigned short* __restrict__ Vt, float* __restrict__ Y) {
  __shared__ float smY[3][64][33];   // 25.3 KB
  __shared__ float smL[4][64];       // 1 KB
  int lane = threadIdx.x & 63;
  int wv = threadIdx.x >> 6;
  int quad = lane >> 4, l16 = lane & 15;
  int bz = blockIdx.y;
  int qrow0 = blockIdx.x * 64;

  short8 qf[4];
#pragma unroll
  for (int f = 0; f < 4; ++f)
    qf[f] = *(const short8*)(Qb + ((size_t)bz * HW + qrow0 + f * 16 + l16) * C2 + quad * 8);
  const unsigned short* kb = Kb + ((size_t)bz * HW4 + wv * 1024) * C2;
  const unsigned short* vb = Vt + (size_t)bz * C2 * HW4 + wv * 1024;

  short8 ones;
#pragma unroll
  for (int i = 0; i < 8; ++i) ones[i] = (short)0x3F80;  // bf16 1.0

  float4v z = {0.f, 0.f, 0.f, 0.f};
  float4v ya[4] = {z, z, z, z};   // y cols l16 (ch 0..15)
  float4v yh[4] = {z, z, z, z};   // y cols 16+l16
  float4v y2[4] = {z, z, z, z};   // row sums l (ones-MFMA)
  float4v moff = {-OFFE, -OFFE, -OFFE, -OFFE};

  for (int t = 0; t < 32; ++t) {
    const unsigned short* kt = kb + (size_t)t * 32 * C2;
    const unsigned short* vt = vb + t * 32;
    short8 ka = *(const short8*)(kt + (size_t)l16 * C2 + quad * 8);
    short8 kh = *(const short8*)(kt + (size_t)(16 + l16) * C2 + quad * 8);
    short8 va = *(const short8*)(vt + (size_t)l16 * HW4 + quad * 8);
    short8 vh = *(const short8*)(vt + (size_t)(16 + l16) * HW4 + quad * 8);
#pragma unroll
    for (int f = 0; f < 4; ++f) {
      float4v sa = __builtin_amdgcn_mfma_f32_16x16x32_bf16(ka, qf[f], moff, 0, 0, 0);
      float4v sh = __builtin_amdgcn_mfma_f32_16x16x32_bf16(kh, qf[f], moff, 0, 0, 0);
      float e0 = __builtin_amdgcn_exp2f(sa[0]), e1 = __builtin_amdgcn_exp2f(sa[1]);
      float e2 = __builtin_amdgcn_exp2f(sa[2]), e3 = __builtin_amdgcn_exp2f(sa[3]);
      float g0 = __builtin_amdgcn_exp2f(sh[0]), g1 = __builtin_amdgcn_exp2f(sh[1]);
      float g2 = __builtin_amdgcn_exp2f(sh[2]), g3 = __builtin_amdgcn_exp2f(sh[3]);
      uint4v d = {packtrunc(e0, e1), packtrunc(e2, e3),
                  packtrunc(g0, g1), packtrunc(g2, g3)};
      short8 pf = __builtin_bit_cast(short8, d);
      ya[f] = __builtin_amdgcn_mfma_f32_16x16x32_bf16(pf, va,   ya[f], 0, 0, 0);
      yh[f] = __builtin_amdgcn_mfma_f32_16x16x32_bf16(pf, vh,   yh[f], 0, 0, 0);
      y2[f] = __builtin_amdgcn_mfma_f32_16x16x32_bf16(pf, ones, y2[f], 0, 0, 0);
    }
  }

  // merge the 4 key quarters
  if (l16 == 0) {
#pragma unroll
    for (int f = 0; f < 4; ++f)
#pragma unroll
      for (int r = 0; r < 4; ++r)
        smL[wv][f * 16 + quad * 4 + r] = y2[f][r];   // cols identical
  }
  if (wv > 0) {
    int pi = wv - 1;
#pragma unroll
    for (int f = 0; f < 4; ++f)
#pragma unroll
      for (int r = 0; r < 4; ++r) {
        int lr = f * 16 + quad * 4 + r;
        smY[pi][lr][l16] = ya[f][r];
        smY[pi][lr][16 + l16] = yh[f][r];
      }
  }
  __syncthreads();
  if (wv == 0) {
#pragma unroll
    for (int f = 0; f < 4; ++f)
#pragma unroll
      for (int r = 0; r < 4; ++r) {
        int lr = f * 16 + quad * 4 + r;
        float a0 = ya[f][r] + smY[0][lr][l16] + smY[1][lr][l16] + smY[2][lr][l16];
        float a1 = yh[f][r] + smY[0][lr][16 + l16] + smY[1][lr][16 + l16] + smY[2][lr][16 + l16];
        float L = smL[0][lr] + smL[1][lr] + smL[2][lr] + smL[3][lr];
        float inv = 1.f / L;
        size_t rw = (size_t)bz * HW + qrow0 + lr;
        Y[rw * C2 + l16] = a0 * inv;
        Y[rw * C2 + 16 + l16] = a1 * inv;
      }
  }
}

// ---------------------------------------------------------------------------
// Kernel 3: output conv (32->64) + bias + residual; cog split x8 (8 ch each)
// -> 2048 blocks = 8 blocks/CU. Y re-reads stay L2-resident (8 MB).
// ---------------------------------------------------------------------------
__global__ __launch_bounds__(256) void conv_out_kern(
    const float* __restrict__ Y, const float* __restrict__ x,
    const float* __restrict__ w, const float* __restrict__ bias,
    float* __restrict__ out) {
  int p = blockIdx.x * 256 + threadIdx.x;
  int cog = blockIdx.y, bz = blockIdx.z;    // cog 0..7 -> channels cog*8..+7
  const float* xb = x + (size_t)bz * Cin * HW + p;
  float xr[8];
#pragma unroll
  for (int i = 0; i < 8; ++i)               // residual loads in flight
    xr[i] = xb[(size_t)(cog * 8 + i) * HW];
  float y[C2];
  const float4* yp4 = (const float4*)(Y + ((size_t)bz * HW + p) * C2);
#pragma unroll
  for (int i = 0; i < 8; ++i) {
    float4 t = yp4[i];
    y[4 * i] = t.x; y[4 * i + 1] = t.y; y[4 * i + 2] = t.z; y[4 * i + 3] = t.w;
  }
  float* ob = out + (size_t)bz * Cin * HW + p;
#pragma unroll
  for (int i = 0; i < 8; ++i) {
    int co = cog * 8 + i;
    float s = bias[co];
#pragma unroll
    for (int o = 0; o < C2; ++o) s = fmaf(w[co * C2 + o], y[o], s);  // s_load
    ob[(size_t)co * HW] = s + xr[i];
  }
}

// ---------------------------------------------------------------------------
extern "C" void kernel_launch(void* const* d_in, const int* in_sizes, int n_in,
                              void* d_out, int out_size, void* d_ws, size_t ws_size,
                              hipStream_t stream) {
  const float* x       = (const float*)d_in[0];
  const float* w_theta = (const float*)d_in[1];
  const float* b_theta = (const float*)d_in[2];
  const float* w_phi   = (const float*)d_in[3];
  const float* b_phi   = (const float*)d_in[4];
  const float* w_g     = (const float*)d_in[5];
  const float* b_g     = (const float*)d_in[6];
  const float* w_out   = (const float*)d_in[7];
  const float* b_out   = (const float*)d_in[8];
  float* out = (float*)d_out;

  float* Yws = (float*)d_ws;                                   // 8 MB fp32
  unsigned short* Qb = (unsigned short*)(Yws + (size_t)4 * HW * C2);
  unsigned short* Kb = Qb + (size_t)4 * HW * C2;
  unsigned short* Vt = Kb + (size_t)4 * HW4 * C2;
  float* wAll = (float*)(Vt + (size_t)4 * HW4 * C2);           // 6144 f
  float* bAll = wAll + 6144;                                   // 96 f

  repack_w_kern<<<25, 256, 0, stream>>>(w_theta, b_theta, w_phi, b_phi,
                                        w_g, b_g, wAll, bAll);
  conv_qkv_kern<<<dim3(64, 4, 4), 256, 0, stream>>>(x, wAll, bAll, Qb, Kb, Vt);
  attn_mfma_kern<<<dim3(HW / 64, 4), 256, 0, stream>>>(Qb, Kb, Vt, Yws);
  conv_out_kern<<<dim3(64, 8, 4), 256, 0, stream>>>(Yws, x, w_out, b_out, out);
}

// Round 13
// 160.142 us; speedup vs baseline: 1.2871x; 1.0181x over previous
//
#include <hip/hip_runtime.h>

#define HW    16384   // 128*128
#define Wh    128
#define Cin   64
#define C2    32
#define HW4   4096    // 64*64

typedef short short8 __attribute__((ext_vector_type(8)));     // 8 bf16 = 4 VGPRs
typedef float float4v __attribute__((ext_vector_type(4)));
typedef unsigned uint4v __attribute__((ext_vector_type(4)));

#define LOG2E 1.44269504f
#define OFFE  43.2808512f   // 30*log2(e): exp(s-30) == exp2(s*log2e - OFFE)

__device__ __forceinline__ unsigned pack2bf16(float lo, float hi) {
  unsigned ul = __builtin_bit_cast(unsigned, lo);
  unsigned uh = __builtin_bit_cast(unsigned, hi);
  ul = (ul + 0x7fffu + ((ul >> 16) & 1u)) >> 16;
  uh = (uh + 0x7fffu + ((uh >> 16) & 1u)) & 0xffff0000u;
  return ul | uh;
}
__device__ __forceinline__ unsigned short f2bf(float f) {
  unsigned u = __builtin_bit_cast(unsigned, f);
  return (unsigned short)((u + 0x7fffu + ((u >> 16) & 1u)) >> 16);
}
// RTZ-truncate two fp32 to bf16, lo in [15:0], hi in [31:16]
__device__ __forceinline__ unsigned packtrunc(float lo, float hi) {
  return __builtin_amdgcn_perm(__builtin_bit_cast(unsigned, hi),
                               __builtin_bit_cast(unsigned, lo), 0x07060302u);
}

// ---------------------------------------------------------------------------
// Kernel 0: weight repack. wAll[og][c][24] = {theta(8, x log2e), phi(8), g(8)}
// ---------------------------------------------------------------------------
__global__ __launch_bounds__(256) void repack_w_kern(
    const float* __restrict__ wt, const float* __restrict__ bt,
    const float* __restrict__ wp, const float* __restrict__ bp,
    const float* __restrict__ wg, const float* __restrict__ bg,
    float* __restrict__ wAll, float* __restrict__ bAll) {
  int idx = blockIdx.x * 256 + threadIdx.x;
  if (idx < 6144) {
    int og = idx / 1536, rem = idx % 1536;
    int c = rem / 24, j = rem % 24;
    int o = og * 8 + (j & 7);
    float v;
    if (j < 8)       v = wt[o * Cin + c] * LOG2E;
    else if (j < 16) v = wp[o * Cin + c];
    else             v = wg[o * Cin + c];
    wAll[idx] = v;
  } else if (idx < 6240) {
    int i2 = idx - 6144;
    int og = i2 / 24, j = i2 % 24;
    int o = og * 8 + (j & 7);
    bAll[i2] = (j < 8) ? bt[o] * LOG2E : (j < 16 ? bp[o] : bg[o]);
  }
}

// ---------------------------------------------------------------------------
// Kernel 1: FUSED theta+phi+g conv (+2x2 maxpool) with LDS-STAGED x.
// The old version did 64 strided (64 KB apart) scalar x-loads per thread —
// uncoalescible, ~90% stall. Now: block = one pooled row = 256 CONTIGUOUS
// full-res pixels; per 8-channel chunk, stage x[8][256] (8 KB) via fully-
// coalesced float4 loads (2/thread), double-buffered (one barrier/chunk);
// compute reads are ds_read_b32 at 2 lanes/bank (free), hidden under the
// 192-FMA block, while next chunk's staging loads are in flight.
// Arithmetic order per output unchanged -> bitwise-identical results.
// ---------------------------------------------------------------------------
__global__ __launch_bounds__(256) void conv_qkv_kern(
    const float* __restrict__ x, const float* __restrict__ wAll,
    const float* __restrict__ bAll, unsigned short* __restrict__ Q,
    unsigned short* __restrict__ K, unsigned short* __restrict__ Vt) {
  __shared__ float smX[2][8][256];               // 16 KB, double-buffered
  __shared__ unsigned short smV[8][64];          // 1 KB
  int tid = threadIdx.x;
  int og = blockIdx.y, bz = blockIdx.z;
  int pxbase = blockIdx.x * 2 * Wh;              // full-res rows 2i, 2i+1
  int jloc = tid >> 2;                           // pooled col 0..63
  int rpar = (tid >> 1) & 1, cpar = tid & 1;
  int myPx = rpar * Wh + 2 * jloc + cpar;        // local pixel 0..255
  const float* xb = x + (size_t)bz * Cin * HW + pxbase;
  const float* wc = wAll + og * 1536;            // uniform -> s_load
  const float* bb = bAll + og * 24;

  // stage chunk: 512 float4 = 256 threads x 2; ch = f>>6, p4 = f&63
  auto stage = [&](int cb8, int buf) {
#pragma unroll
    for (int u = 0; u < 2; ++u) {
      int f = u * 256 + tid;
      int ch = f >> 6, p4 = f & 63;
      *(float4*)&smX[buf][ch][p4 * 4] =
          *(const float4*)(xb + (size_t)(cb8 * 8 + ch) * HW + p4 * 4);
    }
  };

  float acc[24];
#pragma unroll
  for (int k = 0; k < 24; ++k) acc[k] = bb[k];

  stage(0, 0);
  __syncthreads();
  for (int cb8 = 0; cb8 < 8; ++cb8) {
    if (cb8 < 7) stage(cb8 + 1, (cb8 + 1) & 1);  // loads fly over compute
    float xv[8];
#pragma unroll
    for (int u = 0; u < 8; ++u) xv[u] = smX[cb8 & 1][u][myPx];
#pragma unroll
    for (int u = 0; u < 8; ++u) {
#pragma unroll
      for (int k = 0; k < 24; ++k)
        acc[k] = fmaf(wc[(cb8 * 8 + u) * 24 + k], xv[u], acc[k]);
    }
    __syncthreads();                             // staged buf ready for next
  }

  int pp = blockIdx.x * 64 + jloc;               // global pooled pixel
  int p = pxbase + myPx;                         // global full-res pixel
  // theta -> Q
  {
    uint4 up;
    up.x = pack2bf16(acc[0], acc[1]); up.y = pack2bf16(acc[2], acc[3]);
    up.z = pack2bf16(acc[4], acc[5]); up.w = pack2bf16(acc[6], acc[7]);
    *(uint4*)(Q + ((size_t)bz * HW + p) * C2 + og * 8) = up;
  }
  // 2x2 maxpool across lane-mates {4j..4j+3}
  float aP[8], aG[8];
#pragma unroll
  for (int o = 0; o < 8; ++o) {
    float vp = acc[8 + o], vg = acc[16 + o];
    vp = fmaxf(vp, __shfl_xor(vp, 1)); vp = fmaxf(vp, __shfl_xor(vp, 2));
    vg = fmaxf(vg, __shfl_xor(vg, 1)); vg = fmaxf(vg, __shfl_xor(vg, 2));
    aP[o] = vp; aG[o] = vg;
  }
  if ((tid & 3) == 0) {
    int loc = pp & 31, tile = pp >> 5;
    int prow = ((loc & 4) << 2) + ((loc >> 3) << 2) + (loc & 3);   // S^T perm
    uint4 up;
    up.x = pack2bf16(aP[0], aP[1]); up.y = pack2bf16(aP[2], aP[3]);
    up.z = pack2bf16(aP[4], aP[5]); up.w = pack2bf16(aP[6], aP[7]);
    *(uint4*)(K + ((size_t)bz * HW4 + tile * 32 + prow) * C2 + og * 8) = up;
#pragma unroll
    for (int o = 0; o < 8; ++o) smV[o][tid >> 2] = f2bf(aG[o]);
  }
  __syncthreads();
  // coalesced V store: thread t -> channel t>>5, dword t&31 (2 keys)
  {
    int ch = tid >> 5, idx = tid & 31;
    unsigned v = ((unsigned*)smV)[ch * 32 + idx];
    *(unsigned*)(Vt + (size_t)bz * C2 * HW4 + (size_t)(og * 8 + ch) * HW4 +
                 blockIdx.x * 64 + 2 * idx) = v;
  }
}

// ---------------------------------------------------------------------------
// Kernel 2: MFMA flash attention — 64 Q-ROWS (4 fragments) PER WAVE.
// 4 independent QK->exp->PV chains per tile (R12 win: 99 -> 59 µs).
// S^T trick: P emerges in PV A-layout in registers; ones-MFMA computes
// row-sums l on the MFMA pipe, row-aligned with y. No spill at (256,4).
// ---------------------------------------------------------------------------
__global__ __launch_bounds__(256, 4) void attn_mfma_kern(
    const unsigned short* __restrict__ Qb, const unsigned short* __restrict__ Kb,
    const unsigned short* __restrict__ Vt, float* __restrict__ Y) {
  __shared__ float smY[3][64][33];   // 25.3 KB
  __shared__ float smL[4][64];       // 1 KB
  int lane = threadIdx.x & 63;
  int wv = threadIdx.x >> 6;
  int quad = lane >> 4, l16 = lane & 15;
  int bz = blockIdx.y;
  int qrow0 = blockIdx.x * 64;

  short8 qf[4];
#pragma unroll
  for (int f = 0; f < 4; ++f)
    qf[f] = *(const short8*)(Qb + ((size_t)bz * HW + qrow0 + f * 16 + l16) * C2 + quad * 8);
  const unsigned short* kb = Kb + ((size_t)bz * HW4 + wv * 1024) * C2;
  const unsigned short* vb = Vt + (size_t)bz * C2 * HW4 + wv * 1024;

  short8 ones;
#pragma unroll
  for (int i = 0; i < 8; ++i) ones[i] = (short)0x3F80;  // bf16 1.0

  float4v z = {0.f, 0.f, 0.f, 0.f};
  float4v ya[4] = {z, z, z, z};   // y cols l16 (ch 0..15)
  float4v yh[4] = {z, z, z, z};   // y cols 16+l16
  float4v y2[4] = {z, z, z, z};   // row sums l (ones-MFMA)
  float4v moff = {-OFFE, -OFFE, -OFFE, -OFFE};

  for (int t = 0; t < 32; ++t) {
    const unsigned short* kt = kb + (size_t)t * 32 * C2;
    const unsigned short* vt = vb + t * 32;
    short8 ka = *(const short8*)(kt + (size_t)l16 * C2 + quad * 8);
    short8 kh = *(const short8*)(kt + (size_t)(16 + l16) * C2 + quad * 8);
    short8 va = *(const short8*)(vt + (size_t)l16 * HW4 + quad * 8);
    short8 vh = *(const short8*)(vt + (size_t)(16 + l16) * HW4 + quad * 8);
#pragma unroll
    for (int f = 0; f < 4; ++f) {
      float4v sa = __builtin_amdgcn_mfma_f32_16x16x32_bf16(ka, qf[f], moff, 0, 0, 0);
      float4v sh = __builtin_amdgcn_mfma_f32_16x16x32_bf16(kh, qf[f], moff, 0, 0, 0);
      float e0 = __builtin_amdgcn_exp2f(sa[0]), e1 = __builtin_amdgcn_exp2f(sa[1]);
      float e2 = __builtin_amdgcn_exp2f(sa[2]), e3 = __builtin_amdgcn_exp2f(sa[3]);
      float g0 = __builtin_amdgcn_exp2f(sh[0]), g1 = __builtin_amdgcn_exp2f(sh[1]);
      float g2 = __builtin_amdgcn_exp2f(sh[2]), g3 = __builtin_amdgcn_exp2f(sh[3]);
      uint4v d = {packtrunc(e0, e1), packtrunc(e2, e3),
                  packtrunc(g0, g1), packtrunc(g2, g3)};
      short8 pf = __builtin_bit_cast(short8, d);
      ya[f] = __builtin_amdgcn_mfma_f32_16x16x32_bf16(pf, va,   ya[f], 0, 0, 0);
      yh[f] = __builtin_amdgcn_mfma_f32_16x16x32_bf16(pf, vh,   yh[f], 0, 0, 0);
      y2[f] = __builtin_amdgcn_mfma_f32_16x16x32_bf16(pf, ones, y2[f], 0, 0, 0);
    }
  }

  // merge the 4 key quarters
  if (l16 == 0) {
#pragma unroll
    for (int f = 0; f < 4; ++f)
#pragma unroll
      for (int r = 0; r < 4; ++r)
        smL[wv][f * 16 + quad * 4 + r] = y2[f][r];   // cols identical
  }
  if (wv > 0) {
    int pi = wv - 1;
#pragma unroll
    for (int f = 0; f < 4; ++f)
#pragma unroll
      for (int r = 0; r < 4; ++r) {
        int lr = f * 16 + quad * 4 + r;
        smY[pi][lr][l16] = ya[f][r];
        smY[pi][lr][16 + l16] = yh[f][r];
      }
  }
  __syncthreads();
  if (wv == 0) {
#pragma unroll
    for (int f = 0; f < 4; ++f)
#pragma unroll
      for (int r = 0; r < 4; ++r) {
        int lr = f * 16 + quad * 4 + r;
        float a0 = ya[f][r] + smY[0][lr][l16] + smY[1][lr][l16] + smY[2][lr][l16];
        float a1 = yh[f][r] + smY[0][lr][16 + l16] + smY[1][lr][16 + l16] + smY[2][lr][16 + l16];
        float L = smL[0][lr] + smL[1][lr] + smL[2][lr] + smL[3][lr];
        float inv = 1.f / L;
        size_t rw = (size_t)bz * HW + qrow0 + lr;
        Y[rw * C2 + l16] = a0 * inv;
        Y[rw * C2 + 16 + l16] = a1 * inv;
      }
  }
}

// ---------------------------------------------------------------------------
// Kernel 3: output conv (32->64) + bias + residual; cog split x8 (8 ch each)
// -> 2048 blocks = 8 blocks/CU. Y re-reads stay L2-resident (8 MB).
// ---------------------------------------------------------------------------
__global__ __launch_bounds__(256) void conv_out_kern(
    const float* __restrict__ Y, const float* __restrict__ x,
    const float* __restrict__ w, const float* __restrict__ bias,
    float* __restrict__ out) {
  int p = blockIdx.x * 256 + threadIdx.x;
  int cog = blockIdx.y, bz = blockIdx.z;    // cog 0..7 -> channels cog*8..+7
  const float* xb = x + (size_t)bz * Cin * HW + p;
  float xr[8];
#pragma unroll
  for (int i = 0; i < 8; ++i)               // residual loads in flight
    xr[i] = xb[(size_t)(cog * 8 + i) * HW];
  float y[C2];
  const float4* yp4 = (const float4*)(Y + ((size_t)bz * HW + p) * C2);
#pragma unroll
  for (int i = 0; i < 8; ++i) {
    float4 t = yp4[i];
    y[4 * i] = t.x; y[4 * i + 1] = t.y; y[4 * i + 2] = t.z; y[4 * i + 3] = t.w;
  }
  float* ob = out + (size_t)bz * Cin * HW + p;
#pragma unroll
  for (int i = 0; i < 8; ++i) {
    int co = cog * 8 + i;
    float s = bias[co];
#pragma unroll
    for (int o = 0; o < C2; ++o) s = fmaf(w[co * C2 + o], y[o], s);  // s_load
    ob[(size_t)co * HW] = s + xr[i];
  }
}

// ---------------------------------------------------------------------------
extern "C" void kernel_launch(void* const* d_in, const int* in_sizes, int n_in,
                              void* d_out, int out_size, void* d_ws, size_t ws_size,
                              hipStream_t stream) {
  const float* x       = (const float*)d_in[0];
  const float* w_theta = (const float*)d_in[1];
  const float* b_theta = (const float*)d_in[2];
  const float* w_phi   = (const float*)d_in[3];
  const float* b_phi   = (const float*)d_in[4];
  const float* w_g     = (const float*)d_in[5];
  const float* b_g     = (const float*)d_in[6];
  const float* w_out   = (const float*)d_in[7];
  const float* b_out   = (const float*)d_in[8];
  float* out = (float*)d_out;

  float* Yws = (float*)d_ws;                                   // 8 MB fp32
  unsigned short* Qb = (unsigned short*)(Yws + (size_t)4 * HW * C2);
  unsigned short* Kb = Qb + (size_t)4 * HW * C2;
  unsigned short* Vt = Kb + (size_t)4 * HW4 * C2;
  float* wAll = (float*)(Vt + (size_t)4 * HW4 * C2);           // 6144 f
  float* bAll = wAll + 6144;                                   // 96 f

  repack_w_kern<<<25, 256, 0, stream>>>(w_theta, b_theta, w_phi, b_phi,
                                        w_g, b_g, wAll, bAll);
  conv_qkv_kern<<<dim3(64, 4, 4), 256, 0, stream>>>(x, wAll, bAll, Qb, Kb, Vt);
  attn_mfma_kern<<<dim3(HW / 64, 4), 256, 0, stream>>>(Qb, Kb, Vt, Yws);
  conv_out_kern<<<dim3(64, 8, 4), 256, 0, stream>>>(Yws, x, w_out, b_out, out);
}